// Round 7
// baseline (587.858 us; speedup 1.0000x reference)
//
#include <hip/hip_runtime.h>

#define N_NODES 16384
#define M_COND  32768
#define SEGS    16
#define SEGLEN  (M_COND / SEGS)   // 2048
#define CDIM    256

// Opaque IEEE f32 ops: inline asm blocks FMA contraction / reassociation by
// hipcc. Transforms and diffs must be PLAINLY rounded; only the square-sum
// is FMA-chained (matching the reference evaluator's contracted reduce).
__device__ __forceinline__ float fmul_rn(float a, float b) {
    float r; asm("v_mul_f32 %0, %1, %2" : "=v"(r) : "v"(a), "v"(b)); return r;
}
__device__ __forceinline__ float fadd_rn(float a, float b) {
    float r; asm("v_add_f32 %0, %1, %2" : "=v"(r) : "v"(a), "v"(b)); return r;
}
__device__ __forceinline__ float fsub_rn(float a, float b) {
    float r; asm("v_sub_f32 %0, %1, %2" : "=v"(r) : "v"(a), "v"(b)); return r;
}

// ---------------------------------------------------------------------------
// 1) cond coords -> part_c (float4: x,y,z,0). batch col is always 0.
// ---------------------------------------------------------------------------
__global__ __launch_bounds__(256) void k_partc(const int* __restrict__ cond,
                                               float4* __restrict__ partc) {
    int i = blockIdx.x * 256 + threadIdx.x;
    if (i >= M_COND) return;
    int cx = cond[i * 4 + 1], cy = cond[i * 4 + 2], cz = cond[i * 4 + 3];
    float4 p;
    p.x = fmul_rn((float)cx + 0.5f, 0.01f);   // int+0.5f is exact in f32
    p.y = fmul_rn((float)cy + 0.5f, 0.01f);
    p.z = fmul_rn((float)cz + 0.5f, 0.01f);
    p.w = 0.0f;
    partc[i] = p;
}

// ---------------------------------------------------------------------------
// 2) timestep embedding MLP -> tf[256]  (single block)
// ---------------------------------------------------------------------------
__global__ __launch_bounds__(256) void k_tfeats(const float* __restrict__ t,
                                                const float* __restrict__ W_t1,
                                                const float* __restrict__ b_t1,
                                                const float* __restrict__ W_t2,
                                                const float* __restrict__ b_t2,
                                                float* __restrict__ tf) {
    __shared__ float emb[96];
    __shared__ float h1[96];
    int tid = threadIdx.x;
    float tv = t[0];
    if (tid < 48) {
        const float kf = (float)(-9.210340371976184 / 47.0); // -ln(1e4)/(half-1)
        float freq = expf((float)tid * kf);
        float e = tv * freq;
        emb[tid]      = sinf(e);
        emb[tid + 48] = cosf(e);
    }
    __syncthreads();
    if (tid < 96) {
        float acc = b_t1[tid];
        for (int i = 0; i < 96; ++i) acc += emb[i] * W_t1[tid * 96 + i];
        h1[tid] = (acc >= 0.0f) ? acc : 0.1f * acc;
    }
    __syncthreads();
    {
        float acc = b_t2[tid];
        for (int e = 0; e < 96; ++e) acc += h1[e] * W_t2[tid * 96 + e];
        tf[tid] = acc;
    }
}

// ---------------------------------------------------------------------------
// 3) Fold W_l1 @ W_proj -> Wc (256x256), and bc = W_l1@b_proj + b_l1
// ---------------------------------------------------------------------------
__global__ __launch_bounds__(256) void k_wc(const float* __restrict__ W_l1,
                                            const float* __restrict__ W_proj,
                                            const float* __restrict__ b_proj,
                                            const float* __restrict__ b_l1,
                                            float* __restrict__ Wc,
                                            float* __restrict__ bc) {
    int e = blockIdx.x, c = threadIdx.x;
    float acc = 0.0f;
    for (int d = 0; d < CDIM; ++d) acc += W_l1[e * CDIM + d] * W_proj[d * CDIM + c];
    Wc[e * CDIM + c] = acc;
    if (c == 0) {
        float a = b_l1[e];
        for (int d = 0; d < CDIM; ++d) a += W_l1[e * CDIM + d] * b_proj[d];
        bc[e] = a;
    }
}

// ---------------------------------------------------------------------------
// 4) Brute-force segmented KNN. One thread = (node, segment).
//    d2 = fma(dz,dz, fma(dy,dy, rn(dx*dx)))  -- FMA-contracted reduce (the
//    reference evaluator's pattern; the batch term is fma(0,0,0)=0 and the
//    first real step fma(dx,dx,0) rounds once = rn(dx^2)). Transforms and
//    diffs stay plainly rounded (asm-pinned): round 2 showed fusing the
//    transform into the subtract breaks the match.
//    Ties: stable lower-index (jax top_k / stable argsort); rare anyway.
// ---------------------------------------------------------------------------
__global__ __launch_bounds__(256) void k_knn(const int* __restrict__ nodec,
                                             const float4* __restrict__ partc,
                                             float* __restrict__ outd,
                                             int* __restrict__ outi) {
    int node = blockIdx.x * 256 + threadIdx.x;
    int seg  = blockIdx.y;
    int c1 = nodec[node * 4 + 1], c2 = nodec[node * 4 + 2], c3 = nodec[node * 4 + 3];
    float nx = fmul_rn((float)c1 + 8.0f, 0.05f);
    float ny = fmul_rn((float)c2 + 8.0f, 0.05f);
    float nz = fmul_rn((float)c3 + 8.0f, 0.05f);

    float sd[8]; int si[8];
#pragma unroll
    for (int q = 0; q < 8; ++q) { sd[q] = __builtin_inff(); si[q] = 0x7fffffff; }

    int jbeg = seg * SEGLEN, jend = jbeg + SEGLEN;
    for (int j = jbeg; j < jend; ++j) {
        float4 p = partc[j];
        float dx = fsub_rn(nx, p.x);
        float dy = fsub_rn(ny, p.y);
        float dz = fsub_rn(nz, p.z);
        float d2 = __builtin_fmaf(dz, dz,
                     __builtin_fmaf(dy, dy, fmul_rn(dx, dx)));
        if (d2 < sd[7]) {
            float cd = d2; int ci = j;
#pragma unroll
            for (int q = 0; q < 8; ++q) {
                bool cc = cd < sd[q];
                float ns  = cc ? cd : sd[q];
                float ncd = cc ? sd[q] : cd;
                int   nsi = cc ? ci : si[q];
                int   nci = cc ? si[q] : ci;
                sd[q] = ns; si[q] = nsi; cd = ncd; ci = nci;
            }
        }
    }
#pragma unroll
    for (int q = 0; q < 8; ++q) {
        outd[(seg * 8 + q) * N_NODES + node] = sd[q];
        outi[(seg * 8 + q) * N_NODES + node] = si[q];
    }
}

// ---------------------------------------------------------------------------
// 5) Merge SEGS*8 candidates per node -> final top-8, lex (d asc, idx asc)
//    = stable lower-index tie rule; then 1/dist weights normalized.
// ---------------------------------------------------------------------------
__global__ __launch_bounds__(256) void k_merge(const float* __restrict__ ind,
                                               const int* __restrict__ ini,
                                               float* __restrict__ w8,
                                               int* __restrict__ i8) {
    int n = blockIdx.x * 256 + threadIdx.x;
    float sd[8]; int si[8];
#pragma unroll
    for (int q = 0; q < 8; ++q) { sd[q] = __builtin_inff(); si[q] = 0x7fffffff; }

    for (int e = 0; e < SEGS * 8; ++e) {
        float d = ind[e * N_NODES + n];
        int  ii = ini[e * N_NODES + n];
        if (d < sd[7] || (d == sd[7] && ii < si[7])) {
            float cd = d; int ci = ii;
#pragma unroll
            for (int q = 0; q < 8; ++q) {
                bool cc = (cd < sd[q]) || (cd == sd[q] && ci < si[q]);
                float ns  = cc ? cd : sd[q];
                float ncd = cc ? sd[q] : cd;
                int   nsi = cc ? ci : si[q];
                int   nci = cc ? si[q] : ci;
                sd[q] = ns; si[q] = nsi; cd = ncd; ci = nci;
            }
        }
    }

    float w[8]; float s = 0.0f;
#pragma unroll
    for (int q = 0; q < 8; ++q) {
        float dist = __builtin_sqrtf(sd[q]);
        dist = fmaxf(dist, 1e-6f);
        w[q] = 1.0f / dist;
        s += w[q];
    }
#pragma unroll
    for (int q = 0; q < 8; ++q) {
        w8[q * N_NODES + n] = w[q] / s;
        i8[q * N_NODES + n] = si[q];
    }
}

// ---------------------------------------------------------------------------
// 6) fbar[n] = sum_k w_k * feats[idx_k]   (64 lanes per node, float4 lanes)
// ---------------------------------------------------------------------------
__global__ __launch_bounds__(256) void k_fbar(const float* __restrict__ feats,
                                              const float* __restrict__ w8,
                                              const int* __restrict__ i8,
                                              float* __restrict__ fbar) {
    int node = blockIdx.x * 4 + (threadIdx.x >> 6);
    int lane = threadIdx.x & 63;
    int c = lane * 4;
    float4 acc = {0.0f, 0.0f, 0.0f, 0.0f};
#pragma unroll
    for (int q = 0; q < 8; ++q) {
        float w  = w8[q * N_NODES + node];
        int  idx = i8[q * N_NODES + node];
        const float4 f = *(const float4*)&feats[idx * CDIM + c];
        acc.x += w * f.x; acc.y += w * f.y; acc.z += w * f.z; acc.w += w * f.w;
    }
    *(float4*)&fbar[node * CDIM + c] = acc;
}

// ---------------------------------------------------------------------------
// 7) fp32 tiled GEMM: C[n,j] = act(sum_c A[n,c]*W[j,c] + b[j]) (+tf[j])
//    BM=BN=64, BK=16, 256 threads, 4x4 microtile.
// ---------------------------------------------------------------------------
template <bool LEAKY, bool ADDTF>
__global__ __launch_bounds__(256) void k_gemm(const float* __restrict__ A,
                                              const float* __restrict__ W,
                                              const float* __restrict__ bias,
                                              const float* __restrict__ tf,
                                              float* __restrict__ Cmat) {
    __shared__ float As[16][68];
    __shared__ float Bs[16][68];
    int bm = blockIdx.x * 64;
    int bn = blockIdx.y * 64;
    int tid = threadIdx.x;
    int tm = (tid & 15) * 4;
    int tn = (tid >> 4) * 4;
    float acc[4][4] = {};

    int lr = tid >> 2;            // 0..63
    int lc = (tid & 3) * 4;       // 0,4,8,12

    for (int k0 = 0; k0 < CDIM; k0 += 16) {
        float4 a = *(const float4*)&A[(bm + lr) * CDIM + k0 + lc];
        float4 b = *(const float4*)&W[(bn + lr) * CDIM + k0 + lc];
        As[lc + 0][lr] = a.x; As[lc + 1][lr] = a.y; As[lc + 2][lr] = a.z; As[lc + 3][lr] = a.w;
        Bs[lc + 0][lr] = b.x; Bs[lc + 1][lr] = b.y; Bs[lc + 2][lr] = b.z; Bs[lc + 3][lr] = b.w;
        __syncthreads();
#pragma unroll
        for (int k = 0; k < 16; ++k) {
            float4 a4 = *(const float4*)&As[k][tm];
            float4 b4 = *(const float4*)&Bs[k][tn];
            float av[4] = {a4.x, a4.y, a4.z, a4.w};
            float bv[4] = {b4.x, b4.y, b4.z, b4.w};
#pragma unroll
            for (int i = 0; i < 4; ++i)
#pragma unroll
                for (int j = 0; j < 4; ++j) acc[i][j] += av[i] * bv[j];
        }
        __syncthreads();
    }

#pragma unroll
    for (int i = 0; i < 4; ++i) {
#pragma unroll
        for (int j = 0; j < 4; ++j) {
            float v = acc[i][j] + bias[bn + tn + j];
            if (LEAKY) v = (v >= 0.0f) ? v : 0.1f * v;
            if (ADDTF) v += tf[bn + tn + j];
            Cmat[(bm + tm + i) * CDIM + bn + tn + j] = v;
        }
    }
}

// ---------------------------------------------------------------------------
extern "C" void kernel_launch(void* const* d_in, const int* in_sizes, int n_in,
                              void* d_out, int out_size, void* d_ws, size_t ws_size,
                              hipStream_t stream) {
    const int*   nodec  = (const int*)d_in[0];
    const int*   condc  = (const int*)d_in[1];
    const float* feats  = (const float*)d_in[2];
    const float* t      = (const float*)d_in[3];
    const float* W_proj = (const float*)d_in[4];
    const float* b_proj = (const float*)d_in[5];
    const float* W_l1   = (const float*)d_in[6];
    const float* b_l1   = (const float*)d_in[7];
    const float* W_l2   = (const float*)d_in[8];
    const float* b_l2   = (const float*)d_in[9];
    const float* W_t1   = (const float*)d_in[10];
    const float* b_t1   = (const float*)d_in[11];
    const float* W_t2   = (const float*)d_in[12];
    const float* b_t2   = (const float*)d_in[13];
    float* out = (float*)d_out;

    char* ws = (char*)d_ws;
    // workspace layout (bytes), total ~33.8 MB
    float*  tf    = (float*)(ws + 0);                         // 1 KB
    float4* partc = (float4*)(ws + 1024);                     // 512 KB
    float*  Wc    = (float*)(ws + 525312);                    // 256 KB
    float*  bc    = (float*)(ws + 787456);                    // 1 KB
    float*  wsd   = (float*)(ws + 788480);                    // 8 MB
    int*    wsi   = (int*)  (ws + 9177088);                   // 8 MB
    float*  w8    = (float*)(ws + 17565696);                  // 512 KB
    int*    i8    = (int*)  (ws + 18089984);                  // 512 KB
    float*  fbar  = (float*)(ws + 18614272);                  // 16 MB
    float*  h     = (float*)(ws + 788480);                    // reuse KNN scratch (dead after merge)

    k_partc<<<dim3(M_COND / 256), dim3(256), 0, stream>>>(condc, partc);
    k_tfeats<<<dim3(1), dim3(256), 0, stream>>>(t, W_t1, b_t1, W_t2, b_t2, tf);
    k_wc<<<dim3(256), dim3(256), 0, stream>>>(W_l1, W_proj, b_proj, b_l1, Wc, bc);
    k_knn<<<dim3(N_NODES / 256, SEGS), dim3(256), 0, stream>>>(nodec, partc, wsd, wsi);
    k_merge<<<dim3(N_NODES / 256), dim3(256), 0, stream>>>(wsd, wsi, w8, i8);
    k_fbar<<<dim3(N_NODES / 4), dim3(256), 0, stream>>>(feats, w8, i8, fbar);
    k_gemm<true, false><<<dim3(N_NODES / 64, CDIM / 64), dim3(256), 0, stream>>>(fbar, Wc, bc, tf, h);
    k_gemm<false, true><<<dim3(N_NODES / 64, CDIM / 64), dim3(256), 0, stream>>>(h, W_l2, b_l2, tf, out);
}

// Round 8
// 364.671 us; speedup vs baseline: 1.6120x; 1.6120x over previous
//
#include <hip/hip_runtime.h>

#define N_NODES 16384
#define M_COND  32768
#define CDIM    256
#define TILE    1024                 // cond points per LDS tile (SoA)
#define NTILES  (M_COND / TILE)      // 32
#define NPB     8                    // nodes (=waves) per block

// Opaque IEEE f32 ops: inline asm blocks FMA contraction / reassociation.
// Verified recipe (round 7 pass): transforms and diffs plainly rounded,
// square-sum FMA-chained: d2 = fma(dz,dz, fma(dy,dy, rn(dx*dx))).
__device__ __forceinline__ float fmul_rn(float a, float b) {
    float r; asm("v_mul_f32 %0, %1, %2" : "=v"(r) : "v"(a), "v"(b)); return r;
}
__device__ __forceinline__ float fsub_rn(float a, float b) {
    float r; asm("v_sub_f32 %0, %1, %2" : "=v"(r) : "v"(a), "v"(b)); return r;
}

// ---------------------------------------------------------------------------
// 1) cond coords -> SoA planes xs/ys/zs (pinned transform)
// ---------------------------------------------------------------------------
__global__ __launch_bounds__(256) void k_partc(const int* __restrict__ cond,
                                               float* __restrict__ xs,
                                               float* __restrict__ ys,
                                               float* __restrict__ zs) {
    int i = blockIdx.x * 256 + threadIdx.x;
    if (i >= M_COND) return;
    xs[i] = fmul_rn((float)cond[i * 4 + 1] + 0.5f, 0.01f);
    ys[i] = fmul_rn((float)cond[i * 4 + 2] + 0.5f, 0.01f);
    zs[i] = fmul_rn((float)cond[i * 4 + 3] + 0.5f, 0.01f);
}

// ---------------------------------------------------------------------------
// 2) timestep embedding MLP -> tf[256]  (single block)
// ---------------------------------------------------------------------------
__global__ __launch_bounds__(256) void k_tfeats(const float* __restrict__ t,
                                                const float* __restrict__ W_t1,
                                                const float* __restrict__ b_t1,
                                                const float* __restrict__ W_t2,
                                                const float* __restrict__ b_t2,
                                                float* __restrict__ tf) {
    __shared__ float emb[96];
    __shared__ float h1[96];
    int tid = threadIdx.x;
    float tv = t[0];
    if (tid < 48) {
        const float kf = (float)(-9.210340371976184 / 47.0);
        float freq = expf((float)tid * kf);
        float e = tv * freq;
        emb[tid]      = sinf(e);
        emb[tid + 48] = cosf(e);
    }
    __syncthreads();
    if (tid < 96) {
        float acc = b_t1[tid];
        for (int i = 0; i < 96; ++i) acc += emb[i] * W_t1[tid * 96 + i];
        h1[tid] = (acc >= 0.0f) ? acc : 0.1f * acc;
    }
    __syncthreads();
    {
        float acc = b_t2[tid];
        for (int e = 0; e < 96; ++e) acc += h1[e] * W_t2[tid * 96 + e];
        tf[tid] = acc;
    }
}

// ---------------------------------------------------------------------------
// 3) Fold W_l1 @ W_proj -> Wc (256x256), and bc = W_l1@b_proj + b_l1
// ---------------------------------------------------------------------------
__global__ __launch_bounds__(256) void k_wc(const float* __restrict__ W_l1,
                                            const float* __restrict__ W_proj,
                                            const float* __restrict__ b_proj,
                                            const float* __restrict__ b_l1,
                                            float* __restrict__ Wc,
                                            float* __restrict__ bc) {
    int e = blockIdx.x, c = threadIdx.x;
    float acc = 0.0f;
    for (int d = 0; d < CDIM; ++d) acc += W_l1[e * CDIM + d] * W_proj[d * CDIM + c];
    Wc[e * CDIM + c] = acc;
    if (c == 0) {
        float a = b_l1[e];
        for (int d = 0; d < CDIM; ++d) a += W_l1[e * CDIM + d] * b_proj[d];
        bc[e] = a;
    }
}

// ---------------------------------------------------------------------------
// 4) Transposed-wave KNN + fused weights + fbar gather.
//    One WAVE per node; 64 lanes evaluate 64 candidates/step from LDS tiles
//    (SoA, conflict-free). Top-8 lives SORTED ACROSS LANES 0..7; insertion is
//    a uniform ~16-op DPP shift, ~74x per node. Candidates arrive in
//    ascending index, so lex (d2, idx) tie-break reduces to `<=`.
//    d2 recipe bit-identical to the round-7 passing kernel.
// ---------------------------------------------------------------------------
__global__ __launch_bounds__(512) void k_knn(const int* __restrict__ nodec,
                                             const float* __restrict__ xs_g,
                                             const float* __restrict__ ys_g,
                                             const float* __restrict__ zs_g,
                                             const float* __restrict__ feats,
                                             float* __restrict__ fbar) {
    __shared__ float lx[2][TILE], ly[2][TILE], lz[2][TILE];
    const int tid  = threadIdx.x;
    const int wv   = tid >> 6;
    const int lane = tid & 63;
    const int node = blockIdx.x * NPB + wv;

    // node coords (wave-uniform), pinned transform
    int c1 = nodec[node * 4 + 1], c2 = nodec[node * 4 + 2], c3 = nodec[node * 4 + 3];
    float nx = fmul_rn((float)c1 + 8.0f, 0.05f);
    float ny = fmul_rn((float)c2 + 8.0f, 0.05f);
    float nz = fmul_rn((float)c3 + 8.0f, 0.05f);

    float dlist = __builtin_inff();   // lane q (q<8): q-th smallest d2
    int   ilist = 0x7fffffff;         // its candidate index
    float sd7   = __builtin_inff();   // broadcast current 8th-best

    // stage tile 0
    {
        float2 vx = *(const float2*)&xs_g[tid * 2];
        float2 vy = *(const float2*)&ys_g[tid * 2];
        float2 vz = *(const float2*)&zs_g[tid * 2];
        *(float2*)&lx[0][tid * 2] = vx;
        *(float2*)&ly[0][tid * 2] = vy;
        *(float2*)&lz[0][tid * 2] = vz;
    }
    __syncthreads();

    for (int tIdx = 0; tIdx < NTILES; ++tIdx) {
        const int cur = tIdx & 1;
        if (tIdx + 1 < NTILES) {
            const int nxt = cur ^ 1;
            const int g = (tIdx + 1) * TILE + tid * 2;
            float2 vx = *(const float2*)&xs_g[g];
            float2 vy = *(const float2*)&ys_g[g];
            float2 vz = *(const float2*)&zs_g[g];
            *(float2*)&lx[nxt][tid * 2] = vx;
            *(float2*)&ly[nxt][tid * 2] = vy;
            *(float2*)&lz[nxt][tid * 2] = vz;
        }
#pragma unroll
        for (int i = 0; i < TILE / 64; ++i) {
            float px = lx[cur][i * 64 + lane];
            float py = ly[cur][i * 64 + lane];
            float pz = lz[cur][i * 64 + lane];
            float dx = fsub_rn(nx, px);
            float dy = fsub_rn(ny, py);
            float dz = fsub_rn(nz, pz);
            float d2 = __builtin_fmaf(dz, dz,
                         __builtin_fmaf(dy, dy, fmul_rn(dx, dx)));
            unsigned long long m = __ballot(d2 < sd7);
            if (m) {
                do {
                    const int L = __builtin_ctzll(m);
                    m &= m - 1;
                    // candidate (uniform scalars)
                    const float cd = __uint_as_float(
                        __builtin_amdgcn_readlane(__float_as_uint(d2), L));
                    const int cj = tIdx * TILE + i * 64 + L;
                    // insertion position p = #(list keys <= cand key); ties in
                    // d2 keep the (lower-index) incumbent first -> `<=`.
                    bool le = (dlist <= cd);
                    unsigned long long m8 = __ballot(le) & 0xffull;
                    int p = __popcll(m8);
                    // shift lanes >= p right by one (drop lane 7)
                    float shd = __uint_as_float(__builtin_amdgcn_update_dpp(
                        __float_as_uint(dlist), __float_as_uint(dlist),
                        0x111, 0xF, 0xF, false));
                    int shi = __builtin_amdgcn_update_dpp(ilist, ilist,
                        0x111, 0xF, 0xF, false);
                    bool keep = lane < p;
                    bool at   = lane == p;
                    dlist = keep ? dlist : (at ? cd : shd);
                    ilist = keep ? ilist : (at ? cj : shi);
                } while (m);
                sd7 = __uint_as_float(
                    __builtin_amdgcn_readlane(__float_as_uint(dlist), 7));
            }
        }
        __syncthreads();
    }

    // weights (same math as the passing kernel, per-element)
    float dist = __builtin_sqrtf(dlist);
    dist = fmaxf(dist, 1e-6f);
    float w = 1.0f / dist;
    float wm = (lane < 8) ? w : 0.0f;
    wm += __shfl_xor(wm, 1);
    wm += __shfl_xor(wm, 2);
    wm += __shfl_xor(wm, 4);          // lanes 0-7: sum of the 8 weights
    float wn = w / wm;                // valid on lanes 0-7

    // fused fbar: node row = 256 cols, lane covers cols 4*lane..4*lane+3
    const int c = lane * 4;
    float4 acc = {0.0f, 0.0f, 0.0f, 0.0f};
#pragma unroll
    for (int q = 0; q < 8; ++q) {
        float sw  = __uint_as_float(
            __builtin_amdgcn_readlane(__float_as_uint(wn), q));
        int   sid = __builtin_amdgcn_readlane(ilist, q);
        const float4 f = *(const float4*)&feats[sid * CDIM + c];
        acc.x += sw * f.x; acc.y += sw * f.y;
        acc.z += sw * f.z; acc.w += sw * f.w;
    }
    *(float4*)&fbar[node * CDIM + c] = acc;
}

// ---------------------------------------------------------------------------
// 5) fp32 tiled GEMM: C[n,j] = act(sum_c A[n,c]*W[j,c] + b[j]) (+tf[j])
// ---------------------------------------------------------------------------
template <bool LEAKY, bool ADDTF>
__global__ __launch_bounds__(256) void k_gemm(const float* __restrict__ A,
                                              const float* __restrict__ W,
                                              const float* __restrict__ bias,
                                              const float* __restrict__ tf,
                                              float* __restrict__ Cmat) {
    __shared__ float As[16][68];
    __shared__ float Bs[16][68];
    int bm = blockIdx.x * 64;
    int bn = blockIdx.y * 64;
    int tid = threadIdx.x;
    int tm = (tid & 15) * 4;
    int tn = (tid >> 4) * 4;
    float acc[4][4] = {};

    int lr = tid >> 2;
    int lc = (tid & 3) * 4;

    for (int k0 = 0; k0 < CDIM; k0 += 16) {
        float4 a = *(const float4*)&A[(bm + lr) * CDIM + k0 + lc];
        float4 b = *(const float4*)&W[(bn + lr) * CDIM + k0 + lc];
        As[lc + 0][lr] = a.x; As[lc + 1][lr] = a.y; As[lc + 2][lr] = a.z; As[lc + 3][lr] = a.w;
        Bs[lc + 0][lr] = b.x; Bs[lc + 1][lr] = b.y; Bs[lc + 2][lr] = b.z; Bs[lc + 3][lr] = b.w;
        __syncthreads();
#pragma unroll
        for (int k = 0; k < 16; ++k) {
            float4 a4 = *(const float4*)&As[k][tm];
            float4 b4 = *(const float4*)&Bs[k][tn];
            float av[4] = {a4.x, a4.y, a4.z, a4.w};
            float bv[4] = {b4.x, b4.y, b4.z, b4.w};
#pragma unroll
            for (int i = 0; i < 4; ++i)
#pragma unroll
                for (int j = 0; j < 4; ++j) acc[i][j] += av[i] * bv[j];
        }
        __syncthreads();
    }

#pragma unroll
    for (int i = 0; i < 4; ++i) {
#pragma unroll
        for (int j = 0; j < 4; ++j) {
            float v = acc[i][j] + bias[bn + tn + j];
            if (LEAKY) v = (v >= 0.0f) ? v : 0.1f * v;
            if (ADDTF) v += tf[bn + tn + j];
            Cmat[(bm + tm + i) * CDIM + bn + tn + j] = v;
        }
    }
}

// ---------------------------------------------------------------------------
extern "C" void kernel_launch(void* const* d_in, const int* in_sizes, int n_in,
                              void* d_out, int out_size, void* d_ws, size_t ws_size,
                              hipStream_t stream) {
    const int*   nodec  = (const int*)d_in[0];
    const int*   condc  = (const int*)d_in[1];
    const float* feats  = (const float*)d_in[2];
    const float* t      = (const float*)d_in[3];
    const float* W_proj = (const float*)d_in[4];
    const float* b_proj = (const float*)d_in[5];
    const float* W_l1   = (const float*)d_in[6];
    const float* b_l1   = (const float*)d_in[7];
    const float* W_l2   = (const float*)d_in[8];
    const float* b_l2   = (const float*)d_in[9];
    const float* W_t1   = (const float*)d_in[10];
    const float* b_t1   = (const float*)d_in[11];
    const float* W_t2   = (const float*)d_in[12];
    const float* b_t2   = (const float*)d_in[13];
    float* out = (float*)d_out;

    char* ws = (char*)d_ws;
    float* tf   = (float*)(ws + 0);               // 1 KB
    float* xs_g = (float*)(ws + 1024);            // 128 KB
    float* ys_g = (float*)(ws + 132096);          // 128 KB
    float* zs_g = (float*)(ws + 263168);          // 128 KB
    float* Wc   = (float*)(ws + 394240);          // 256 KB
    float* bc   = (float*)(ws + 656384);          // 1 KB
    float* fbar = (float*)(ws + 657408);          // 16 MB
    float* h    = (float*)(ws + 17434624);        // 16 MB

    k_partc<<<dim3(M_COND / 256), dim3(256), 0, stream>>>(condc, xs_g, ys_g, zs_g);
    k_tfeats<<<dim3(1), dim3(256), 0, stream>>>(t, W_t1, b_t1, W_t2, b_t2, tf);
    k_wc<<<dim3(256), dim3(256), 0, stream>>>(W_l1, W_proj, b_proj, b_l1, Wc, bc);
    k_knn<<<dim3(N_NODES / NPB), dim3(512), 0, stream>>>(nodec, xs_g, ys_g, zs_g, feats, fbar);
    k_gemm<true, false><<<dim3(N_NODES / 64, CDIM / 64), dim3(256), 0, stream>>>(fbar, Wc, bc, tf, h);
    k_gemm<false, true><<<dim3(N_NODES / 64, CDIM / 64), dim3(256), 0, stream>>>(h, W_l2, b_l2, tf, out);
}

// Round 10
// 291.513 us; speedup vs baseline: 2.0166x; 1.2510x over previous
//
#include <hip/hip_runtime.h>

#define N_NODES 16384
#define M_COND  32768
#define CDIM    256
#define GD      8                    // grid cells per axis
#define GCELLS  (GD * GD * GD)       // 512
#define CELLW   1.28f                // 128 lattice units * 0.01
#define FINF    __builtin_inff()

// Opaque IEEE f32 ops: block FMA contraction. Verified recipe (rounds 7/8):
// transforms and diffs plainly rounded, square-sum FMA-chained.
__device__ __forceinline__ float fmul_rn(float a, float b) {
    float r; asm("v_mul_f32 %0, %1, %2" : "=v"(r) : "v"(a), "v"(b)); return r;
}
__device__ __forceinline__ float fsub_rn(float a, float b) {
    float r; asm("v_sub_f32 %0, %1, %2" : "=v"(r) : "v"(a), "v"(b)); return r;
}

// ---------------------------------------------------------------------------
// Grid build: zero -> histogram -> scan -> scatter (counting sort by cell).
// Cell id is EXACT integer: ((cx>>7)<<6) | ((cy>>7)<<3) | (cz>>7).
// Within-cell order is atomic-nondeterministic; selection is order-
// independent (full lex (d2, original idx) compares in the query).
// ---------------------------------------------------------------------------
__global__ __launch_bounds__(512) void k_zero(int* __restrict__ counts) {
    counts[threadIdx.x] = 0;
}

__global__ __launch_bounds__(256) void k_count(const int* __restrict__ cond,
                                               int* __restrict__ counts) {
    int i = blockIdx.x * 256 + threadIdx.x;
    if (i >= M_COND) return;
    int cell = ((cond[i*4+1] >> 7) << 6) | ((cond[i*4+2] >> 7) << 3) | (cond[i*4+3] >> 7);
    atomicAdd(&counts[cell], 1);
}

__global__ __launch_bounds__(512) void k_scan(const int* __restrict__ counts,
                                              int* __restrict__ starts,
                                              int* __restrict__ cursor) {
    __shared__ int s[GCELLS];
    int tid = threadIdx.x;
    int c = counts[tid];
    s[tid] = c;
    __syncthreads();
    for (int d = 1; d < GCELLS; d <<= 1) {
        int v = (tid >= d) ? s[tid - d] : 0;
        __syncthreads();
        s[tid] += v;
        __syncthreads();
    }
    int excl = s[tid] - c;
    starts[tid] = excl;
    cursor[tid] = excl;
}

__global__ __launch_bounds__(256) void k_scatter(const int* __restrict__ cond,
                                                 int* __restrict__ cursor,
                                                 float* __restrict__ sx,
                                                 float* __restrict__ sy,
                                                 float* __restrict__ sz,
                                                 int* __restrict__ spidx) {
    int i = blockIdx.x * 256 + threadIdx.x;
    if (i >= M_COND) return;
    int cx = cond[i*4+1], cy = cond[i*4+2], cz = cond[i*4+3];
    int cell = ((cx >> 7) << 6) | ((cy >> 7) << 3) | (cz >> 7);
    int pos = atomicAdd(&cursor[cell], 1);
    sx[pos] = fmul_rn((float)cx + 0.5f, 0.01f);   // pinned transform
    sy[pos] = fmul_rn((float)cy + 0.5f, 0.01f);
    sz[pos] = fmul_rn((float)cz + 0.5f, 0.01f);
    spidx[pos] = i;
}

// ---------------------------------------------------------------------------
// timestep embedding MLP -> tf[256]  (single block)
// ---------------------------------------------------------------------------
__global__ __launch_bounds__(256) void k_tfeats(const float* __restrict__ t,
                                                const float* __restrict__ W_t1,
                                                const float* __restrict__ b_t1,
                                                const float* __restrict__ W_t2,
                                                const float* __restrict__ b_t2,
                                                float* __restrict__ tf) {
    __shared__ float emb[96];
    __shared__ float h1[96];
    int tid = threadIdx.x;
    float tv = t[0];
    if (tid < 48) {
        const float kf = (float)(-9.210340371976184 / 47.0);
        float freq = expf((float)tid * kf);
        float e = tv * freq;
        emb[tid]      = sinf(e);
        emb[tid + 48] = cosf(e);
    }
    __syncthreads();
    if (tid < 96) {
        float acc = b_t1[tid];
        for (int i = 0; i < 96; ++i) acc += emb[i] * W_t1[tid * 96 + i];
        h1[tid] = (acc >= 0.0f) ? acc : 0.1f * acc;
    }
    __syncthreads();
    {
        float acc = b_t2[tid];
        for (int e = 0; e < 96; ++e) acc += h1[e] * W_t2[tid * 96 + e];
        tf[tid] = acc;
    }
}

// ---------------------------------------------------------------------------
// Fold W_l1 @ W_proj -> Wc (256x256), and bc = W_l1@b_proj + b_l1
// ---------------------------------------------------------------------------
__global__ __launch_bounds__(256) void k_wc(const float* __restrict__ W_l1,
                                            const float* __restrict__ W_proj,
                                            const float* __restrict__ b_proj,
                                            const float* __restrict__ b_l1,
                                            float* __restrict__ Wc,
                                            float* __restrict__ bc) {
    int e = blockIdx.x, c = threadIdx.x;
    float acc = 0.0f;
    for (int d = 0; d < CDIM; ++d) acc += W_l1[e * CDIM + d] * W_proj[d * CDIM + c];
    Wc[e * CDIM + c] = acc;
    if (c == 0) {
        float a = b_l1[e];
        for (int d = 0; d < CDIM; ++d) a += W_l1[e * CDIM + d] * b_proj[d];
        bc[e] = a;
    }
}

// ---------------------------------------------------------------------------
// Grid-pruned transposed-wave KNN + fused weights + fbar gather.
// One WAVE per node. Phase 1: AABB min-dist^2 to all 512 cells (8 slots/lane;
// empty cells = INF). Phase 2: extract nearest unprocessed cell via lex
// shfl_xor argmin; scan its points (coalesced, 64/step) maintaining the
// cross-lane sorted top-8 (full lex (d2, idx) compares -> order-independent);
// stop when next cell mind2 > sd7*1.0001+1e-3 (conservative vs f32 AABB
// rounding; d2==sd7 tie candidates always survive pruning since mind2<=d2).
// d2 recipe bit-identical to the passing rounds-7/8 kernels.
// ---------------------------------------------------------------------------
__global__ __launch_bounds__(256) void k_knng(const int* __restrict__ nodec,
                                              const float* __restrict__ sx,
                                              const float* __restrict__ sy,
                                              const float* __restrict__ sz,
                                              const int* __restrict__ spidx,
                                              const int* __restrict__ starts,
                                              const int* __restrict__ counts,
                                              const float* __restrict__ feats,
                                              float* __restrict__ fbar) {
    const int tid  = threadIdx.x;
    const int wv   = tid >> 6;
    const int lane = tid & 63;
    const int node = blockIdx.x * 4 + wv;

    int c1 = nodec[node*4+1], c2 = nodec[node*4+2], c3 = nodec[node*4+3];
    float nx = fmul_rn((float)c1 + 8.0f, 0.05f);   // pinned transform
    float ny = fmul_rn((float)c2 + 8.0f, 0.05f);
    float nz = fmul_rn((float)c3 + 8.0f, 0.05f);

    // Phase 1: per-lane 8 cell slots: cell = lane*8 + s
    // i = lane>>3, j = lane&7, k = s ; AABB dist (plain f32, margin covers it)
    float m0, m1, m2, m3, m4, m5, m6, m7;
    {
        float li = (float)(lane >> 3) * CELLW, hi_ = li + CELLW;
        float lj = (float)(lane & 7) * CELLW,  hj = lj + CELLW;
        float dxi = fmaxf(fmaxf(li - nx, nx - hi_), 0.0f);
        float dyj = fmaxf(fmaxf(lj - ny, ny - hj), 0.0f);
        float base = dxi * dxi + dyj * dyj;
        const int4 ca = ((const int4*)counts)[lane * 2];
        const int4 cb = ((const int4*)counts)[lane * 2 + 1];
#define MK(s, cnt) { float lk = (float)(s) * CELLW; \
        float dzk = fmaxf(fmaxf(lk - nz, nz - (lk + CELLW)), 0.0f); \
        float v = base + dzk * dzk; \
        m##s = (cnt > 0) ? v : FINF; }
        MK(0, ca.x) MK(1, ca.y) MK(2, ca.z) MK(3, ca.w)
        MK(4, cb.x) MK(5, cb.y) MK(6, cb.z) MK(7, cb.w)
#undef MK
    }

    float dlist = FINF;               // lane q (q<8): q-th smallest d2 (lex)
    int   ilist = 0x7fffffff;         // its ORIGINAL cond index
    float sd7 = FINF;  int si7 = 0x7fffffff;

    for (;;) {
        // extract nearest unprocessed cell (lex tie by cell id)
        float bv = m0; int bs = 0;
        if (m1 < bv) { bv = m1; bs = 1; }
        if (m2 < bv) { bv = m2; bs = 2; }
        if (m3 < bv) { bv = m3; bs = 3; }
        if (m4 < bv) { bv = m4; bs = 4; }
        if (m5 < bv) { bv = m5; bs = 5; }
        if (m6 < bv) { bv = m6; bs = 6; }
        if (m7 < bv) { bv = m7; bs = 7; }
        float v = bv; int id = lane * 8 + bs;
        for (int o = 32; o; o >>= 1) {
            float ov = __shfl_xor(v, o);
            int   oi = __shfl_xor(id, o);
            if (ov < v || (ov == v && oi < id)) { v = ov; id = oi; }
        }
        if (v >= 1e30f) break;                          // all cells done
        if (v > sd7 * 1.0001f + 1e-3f) break;           // conservative prune

        // mark processed (id is wave-uniform)
        {
            int ol = id >> 3, os = id & 7;
            if (lane == ol) {
                if      (os == 0) m0 = FINF; else if (os == 1) m1 = FINF;
                else if (os == 2) m2 = FINF; else if (os == 3) m3 = FINF;
                else if (os == 4) m4 = FINF; else if (os == 5) m5 = FINF;
                else if (os == 6) m6 = FINF; else              m7 = FINF;
            }
        }

        int start = starts[id];
        int cnt   = counts[id];
        for (int off = 0; off < cnt; off += 64) {
            int  o  = off + lane;
            bool ok = o < cnt;
            int  g  = start + (ok ? o : 0);
            float px = sx[g], py = sy[g], pz = sz[g];
            int   cj = ok ? spidx[g] : 0x7fffffff;
            float dx = fsub_rn(nx, px);
            float dy = fsub_rn(ny, py);
            float dz = fsub_rn(nz, pz);
            float d2 = __builtin_fmaf(dz, dz,
                         __builtin_fmaf(dy, dy, fmul_rn(dx, dx)));
            if (!ok) d2 = FINF;
            unsigned long long m =
                __ballot(d2 < sd7 || (d2 == sd7 && cj < si7));
            if (m) {
                do {
                    const int L = __builtin_ctzll(m);
                    m &= m - 1;
                    const float cd = __uint_as_float(
                        __builtin_amdgcn_readlane(__float_as_uint(d2), L));
                    const int   ci = __builtin_amdgcn_readlane(cj, L);
                    // insertion position: #(list lex-keys <= candidate)
                    bool le = (dlist < cd) || (dlist == cd && ilist < ci);
                    unsigned long long m8 = __ballot(le) & 0xffull;
                    int p = __popcll(m8);
                    float shd = __uint_as_float(__builtin_amdgcn_update_dpp(
                        __float_as_uint(dlist), __float_as_uint(dlist),
                        0x111, 0xF, 0xF, false));
                    int shi = __builtin_amdgcn_update_dpp(ilist, ilist,
                        0x111, 0xF, 0xF, false);
                    bool keep = lane < p;
                    bool at   = lane == p;
                    dlist = keep ? dlist : (at ? cd : shd);
                    ilist = keep ? ilist : (at ? ci : shi);
                } while (m);
                sd7 = __uint_as_float(
                    __builtin_amdgcn_readlane(__float_as_uint(dlist), 7));
                si7 = __builtin_amdgcn_readlane(ilist, 7);
            }
        }
    }

    // weights (identical math to passing kernel)
    float dist = __builtin_sqrtf(dlist);
    dist = fmaxf(dist, 1e-6f);
    float w = 1.0f / dist;
    float wm = (lane < 8) ? w : 0.0f;
    wm += __shfl_xor(wm, 1);
    wm += __shfl_xor(wm, 2);
    wm += __shfl_xor(wm, 4);
    float wn = w / wm;

    // fused fbar gather: lane covers cols 4*lane..4*lane+3
    const int c = lane * 4;
    float4 acc = {0.0f, 0.0f, 0.0f, 0.0f};
#pragma unroll
    for (int q = 0; q < 8; ++q) {
        float sw  = __uint_as_float(
            __builtin_amdgcn_readlane(__float_as_uint(wn), q));
        int   sid = __builtin_amdgcn_readlane(ilist, q);
        const float4 f = *(const float4*)&feats[sid * CDIM + c];
        acc.x += sw * f.x; acc.y += sw * f.y;
        acc.z += sw * f.z; acc.w += sw * f.w;
    }
    *(float4*)&fbar[node * CDIM + c] = acc;
}

// ---------------------------------------------------------------------------
// fp32 tiled GEMM: C[n,j] = act(sum_c A[n,c]*W[j,c] + b[j]) (+tf[j])
// ---------------------------------------------------------------------------
template <bool LEAKY, bool ADDTF>
__global__ __launch_bounds__(256) void k_gemm(const float* __restrict__ A,
                                              const float* __restrict__ W,
                                              const float* __restrict__ bias,
                                              const float* __restrict__ tf,
                                              float* __restrict__ Cmat) {
    __shared__ float As[16][68];
    __shared__ float Bs[16][68];
    int bm = blockIdx.x * 64;
    int bn = blockIdx.y * 64;
    int tid = threadIdx.x;
    int tm = (tid & 15) * 4;
    int tn = (tid >> 4) * 4;
    float acc[4][4] = {};

    int lr = tid >> 2;
    int lc = (tid & 3) * 4;

    for (int k0 = 0; k0 < CDIM; k0 += 16) {
        float4 a = *(const float4*)&A[(bm + lr) * CDIM + k0 + lc];
        float4 b = *(const float4*)&W[(bn + lr) * CDIM + k0 + lc];
        As[lc + 0][lr] = a.x; As[lc + 1][lr] = a.y; As[lc + 2][lr] = a.z; As[lc + 3][lr] = a.w;
        Bs[lc + 0][lr] = b.x; Bs[lc + 1][lr] = b.y; Bs[lc + 2][lr] = b.z; Bs[lc + 3][lr] = b.w;
        __syncthreads();
#pragma unroll
        for (int k = 0; k < 16; ++k) {
            float4 a4 = *(const float4*)&As[k][tm];
            float4 b4 = *(const float4*)&Bs[k][tn];
            float av[4] = {a4.x, a4.y, a4.z, a4.w};
            float bv[4] = {b4.x, b4.y, b4.z, b4.w};
#pragma unroll
            for (int i = 0; i < 4; ++i)
#pragma unroll
                for (int j = 0; j < 4; ++j) acc[i][j] += av[i] * bv[j];
        }
        __syncthreads();
    }

#pragma unroll
    for (int i = 0; i < 4; ++i) {
#pragma unroll
        for (int j = 0; j < 4; ++j) {
            float v = acc[i][j] + bias[bn + tn + j];
            if (LEAKY) v = (v >= 0.0f) ? v : 0.1f * v;
            if (ADDTF) v += tf[bn + tn + j];
            Cmat[(bm + tm + i) * CDIM + bn + tn + j] = v;
        }
    }
}

// ---------------------------------------------------------------------------
extern "C" void kernel_launch(void* const* d_in, const int* in_sizes, int n_in,
                              void* d_out, int out_size, void* d_ws, size_t ws_size,
                              hipStream_t stream) {
    const int*   nodec  = (const int*)d_in[0];
    const int*   condc  = (const int*)d_in[1];
    const float* feats  = (const float*)d_in[2];
    const float* t      = (const float*)d_in[3];
    const float* W_proj = (const float*)d_in[4];
    const float* b_proj = (const float*)d_in[5];
    const float* W_l1   = (const float*)d_in[6];
    const float* b_l1   = (const float*)d_in[7];
    const float* W_l2   = (const float*)d_in[8];
    const float* b_l2   = (const float*)d_in[9];
    const float* W_t1   = (const float*)d_in[10];
    const float* b_t1   = (const float*)d_in[11];
    const float* W_t2   = (const float*)d_in[12];
    const float* b_t2   = (const float*)d_in[13];
    float* out = (float*)d_out;

    char* ws = (char*)d_ws;
    int*   counts = (int*)  (ws + 0);             // 2 KB
    int*   startsA= (int*)  (ws + 2048);          // 2 KB
    int*   cursor = (int*)  (ws + 4096);          // 2 KB
    float* tf     = (float*)(ws + 6144);          // 1 KB
    float* Wc     = (float*)(ws + 7168);          // 256 KB
    float* bc     = (float*)(ws + 269312);        // 1 KB
    float* sxp    = (float*)(ws + 270336);        // 128 KB
    float* syp    = (float*)(ws + 401408);        // 128 KB
    float* szp    = (float*)(ws + 532480);        // 128 KB
    int*   spidx  = (int*)  (ws + 663552);        // 128 KB
    float* fbar   = (float*)(ws + 794624);        // 16 MB
    float* h      = (float*)(ws + 17571840);      // 16 MB

    k_zero<<<dim3(1), dim3(512), 0, stream>>>(counts);
    k_tfeats<<<dim3(1), dim3(256), 0, stream>>>(t, W_t1, b_t1, W_t2, b_t2, tf);
    k_wc<<<dim3(256), dim3(256), 0, stream>>>(W_l1, W_proj, b_proj, b_l1, Wc, bc);
    k_count<<<dim3(M_COND / 256), dim3(256), 0, stream>>>(condc, counts);
    k_scan<<<dim3(1), dim3(512), 0, stream>>>(counts, startsA, cursor);
    k_scatter<<<dim3(M_COND / 256), dim3(256), 0, stream>>>(condc, cursor, sxp, syp, szp, spidx);
    k_knng<<<dim3(N_NODES / 4), dim3(256), 0, stream>>>(nodec, sxp, syp, szp, spidx, startsA, counts, feats, fbar);
    k_gemm<true, false><<<dim3(N_NODES / 64, CDIM / 64), dim3(256), 0, stream>>>(fbar, Wc, bc, tf, h);
    k_gemm<false, true><<<dim3(N_NODES / 64, CDIM / 64), dim3(256), 0, stream>>>(h, W_l2, b_l2, tf, out);
}